// Round 11
// baseline (193.218 us; speedup 1.0000x reference)
//
#include <hip/hip_runtime.h>
#include <math.h>

// Neural Additive Model: 256 per-feature MLPs 1->128->64->32->1 (ReLU), summed.
// B=8192, fp32 in/out.
//
// Exact rank-table decomposition: pre-relu h2[b,k] = x_b*Sw[r,k] + Sb[r,k],
// r = #(sorted layer-1 thresholds < x_b). Layer 3 on f16 MFMA 32x32x16
// (A=W3^T, B=h2), layer 4 reduced in-register + permlane + 1 atomic/elem.
//
// Round 28: RANK-SORTED PHASE 2. Eleven rounds of evidence: phase 2 is
// bound by the per-CU LDS pipe (R23), and SQ_LDS_BANK_CONFLICT has sat at
// 8.0M cycles (~13us/block of pipe time) through every restructure. The
// conflicts come from RANDOM per-lane rank r in the table gather -- no
// static layout fixes a data-dependent address pattern (R22). But rankof(x)
// is monotone and out[] is atomic-accumulated, so elements can be processed
// in ANY order: counting-sort the 8192 elements by rank (phase 1.5, in-LDS
// hist of 129 bins + scatter of perm words b|(r<<16) into ws), and have
// each wave walk its sorted slice. A 32-element sorted window spans ~1-2
// ranks (8192/129~63/rank) -> the 8 ds_read_b128 become same-address
// BROADCASTS (free, m136), and the per-element rank walk leaves phase 2
// entirely (r rides in the perm word). x comes from the L1-resident 32-KB
// xrow via gather. Same math, same single atomic per element (distinct
// addresses -> no R26 serialization). Keeps: R21 two-kernel structure,
// 17-uint4 table, xT transpose + fused out-init, permlane epilogue (R27).

#define NF   256
#define NH1  128
#define NH2  64
#define NH3  32
#define NB   8192

#define NRANK 129
#define ROW4  17                      // uint4 per table row (16 data + 1 pad)
#define ROWH  136                     // halfwords per row

typedef float    f32x16 __attribute__((ext_vector_type(16)));
typedef unsigned u32x4  __attribute__((ext_vector_type(4)));
typedef _Float16 h16x2  __attribute__((ext_vector_type(2)));
typedef _Float16 h16x8  __attribute__((ext_vector_type(8)));

// h2 pair: relu(x*Sw + Sb) on 2 packed f16 channels -> one B-frag dword
__device__ __forceinline__ unsigned pkh2(unsigned sw, unsigned sb, h16x2 xh) {
    h16x2 r = __builtin_elementwise_fma(xh, __builtin_bit_cast(h16x2, sw),
                                            __builtin_bit_cast(h16x2, sb));
    h16x2 hz = {(_Float16)0.f, (_Float16)0.f};
    return __builtin_bit_cast(unsigned, __builtin_elementwise_max(r, hz));
}

// ---------------- transpose: x[B][F] -> xT[F][B] in ws; fuses out-init ----------------
__global__ __launch_bounds__(1024) void transpose_x(
    const float* __restrict__ x, const float* __restrict__ bias,
    float* __restrict__ out, float* __restrict__ xt)
{
    __shared__ float xtile[64][65];        // padded -> conflict-free
    const int t = (int)threadIdx.x;
    const int T = blockIdx.x;              // 0..511
    const int bt = T >> 2, ft = T & 3;     // batch tile 0..127, feat tile 0..3

    if (T < 8) out[T * 1024 + t] = bias[0];   // out poisoned each launch

    #pragma unroll
    for (int it = 0; it < 4; ++it) {
        int idx = t + it * 1024;               // 4096 elems per tile
        int rr = idx >> 6, cc = idx & 63;      // read x[bt*64+rr][ft*64+cc]
        xtile[rr][cc] = x[(size_t)(bt * 64 + rr) * NF + ft * 64 + cc];
    }
    __syncthreads();
    #pragma unroll
    for (int it = 0; it < 4; ++it) {
        int idx = t + it * 1024;
        int cc = idx >> 6, rr = idx & 63;      // write xT[ft*64+cc][bt*64+rr]
        xt[(size_t)(ft * 64 + cc) * NB + bt * 64 + rr] = xtile[rr][cc];
    }
}

// ---------------- fused: one block (1024 thr) per feature ----------------
__global__ __launch_bounds__(1024) void nam_fused(
    const float* __restrict__ W1, const float* __restrict__ b1,
    const float* __restrict__ W2, const float* __restrict__ b2,
    const float* __restrict__ W3, const float* __restrict__ b3,
    const float* __restrict__ W4, const float* __restrict__ b4,
    const float* __restrict__ xt, unsigned* __restrict__ perm,
    float* __restrict__ out)
{
    __shared__ u32x4 SP4[NRANK * ROW4];    // 35.1 KB packed f16 table
    __shared__ float rkey[NH1];            // raw thresholds
    __shared__ float skey[NH1];            // sorted thresholds
    __shared__ int   sidx[NH1];            // sorted payload (channel idx)
    __shared__ float w1s[NH1], b1s[NH1];
    __shared__ float Pbw[16][NH2], Pbb[16][NH2], Pdw[16][NH2], Pdb[16][NH2]; // 16 KB
    __shared__ float lv8[8], lv4[16], lv2[32], lv1[64];  // dense walk levels
    __shared__ unsigned hist[132];         // rank histogram / scatter cursors

    const int f = blockIdx.x;
    const int t = (int)threadIdx.x;
    _Float16* SPh = (_Float16*)SP4;

    // ======== phase 1: build table (R21-proven math) ========
    const float* __restrict__ gw2 = W2 + (size_t)f * NH1 * NH2;
    if (t < NH1) {
        float w  = W1[f * NH1 + t];
        float bb = b1[f * NH1 + t];
        w1s[t] = w; b1s[t] = bb;
        rkey[t] = (w != 0.0f) ? (-bb / w) : INFINITY;   // w==0: never toggled
    }
    if (t >= 1024 - 132) hist[t - (1024 - 132)] = 0;    // zero hist (spare thr)
    __syncthreads();

    // counting-rank sort: 128 threads, each ranks its key vs all 128
    if (t < NH1) {
        const float my = rkey[t];
        int rk = 0;
        #pragma unroll 16
        for (int i = 0; i < NH1; ++i) {
            float ki = rkey[i];
            rk += (ki < my || (ki == my && i < t)) ? 1 : 0;
        }
        skey[rk] = my; sidx[rk] = t;
    }
    __syncthreads();

    // dense walk levels (conflict-free rankof): consecutive addrs -> banks
    if (t < 8)            lv8[t]      = skey[t * 16 + 7];
    else if (t < 24)      lv4[t - 8]  = skey[(t - 8) * 8 + 3];
    else if (t < 56)      lv2[t - 24] = skey[(t - 24) * 4 + 1];
    else if (t < 120)     lv1[t - 56] = skey[(t - 56) * 2];

    // chunked scan: 1024 threads = (k = t&63) x (chunk c = t>>6, 8 j/ranks each)
    {
        const int k = t & 63, c = t >> 6;
        float bw = 0.0f, bbp = 0.0f, dw = 0.0f, db = 0.0f;
        #pragma unroll
        for (int i = 0; i < 8; ++i) {
            int j = c * 8 + i;    // rank-0 base: w<0 active; w==0&&b>0 const-on
            float w = w1s[j], bv = b1s[j], w2v = gw2[j * NH2 + k];
            if (w < 0.0f) { bw = fmaf(w, w2v, bw); bbp = fmaf(bv, w2v, bbp); }
            else if (w == 0.0f && bv > 0.0f) { bbp = fmaf(bv, w2v, bbp); }
            int jj = sidx[c * 8 + i];   // toggle-delta partial
            float ww = w1s[jj], bv2 = b1s[jj], w2x = gw2[jj * NH2 + k];
            float s = (ww > 0.0f) ? 1.0f : ((ww < 0.0f) ? -1.0f : 0.0f);
            dw = fmaf(s * ww,  w2x, dw);
            db = fmaf(s * bv2, w2x, db);
        }
        Pbw[c][k] = bw; Pbb[c][k] = bbp; Pdw[c][k] = dw; Pdb[c][k] = db;
    }
    __syncthreads();
    {
        const int k = t & 63, c = t >> 6;
        float accw = 0.0f;
        float accb = b2[f * NH2 + k];    // b2 seed (round-8 lesson)
        #pragma unroll
        for (int c2 = 0; c2 < 16; ++c2) { accw += Pbw[c2][k]; accb += Pbb[c2][k]; }
        for (int c2 = 0; c2 < c; ++c2) { accw += Pdw[c2][k]; accb += Pdb[c2][k]; }
        // layout per row: Sw halves [0..63], Sb halves [64..127], pad to 136
        if (c == 0) {
            SPh[k]      = (_Float16)accw;          // rank-0 row
            SPh[64 + k] = (_Float16)accb;
        }
        #pragma unroll
        for (int i = 0; i < 8; ++i) {
            int r = c * 8 + i;
            int j = sidx[r];                       // uniform per chunk -> broadcast
            float w = w1s[j], bv = b1s[j], w2v = gw2[j * NH2 + k];
            float s = (w > 0.0f) ? 1.0f : ((w < 0.0f) ? -1.0f : 0.0f);
            accw = fmaf(s * w,  w2v, accw);
            accb = fmaf(s * bv, w2v, accb);
            SPh[(r + 1) * ROWH + k]      = (_Float16)accw;
            SPh[(r + 1) * ROWH + 64 + k] = (_Float16)accb;
        }
    }
    __syncthreads();

    // ======== phase 1.5: rank all 8192 elems, counting-sort into perm ========
    const float* __restrict__ xrow = xt + (size_t)f * NB;
    unsigned* __restrict__ permf = perm + (size_t)f * NB;
    // register-tree search levels s=64/32/16 (7 thresholds)
    const float t63 = skey[63], t31 = skey[31], t95 = skey[95];
    const float t15 = skey[15], t47 = skey[47], t79 = skey[79], t111 = skey[111];
    auto rankof = [&](float q) -> int {
        int rr = (t63 < q) ? 64 : 0;
        {
            float l1 = (rr & 64) ? t95 : t31;
            if (l1 < q) rr += 32;
            float m0 = (rr & 64) ? t79  : t15;
            float m1 = (rr & 64) ? t111 : t47;
            float l2 = (rr & 32) ? m1 : m0;
            if (l2 < q) rr += 16;
        }
        if (lv8[rr >> 4] < q) rr += 8;
        if (lv4[rr >> 3] < q) rr += 4;
        if (lv2[rr >> 2] < q) rr += 2;
        if (lv1[rr >> 1] < q) rr += 1;
        return rr;
    };

    int myr[8];
    #pragma unroll
    for (int i = 0; i < 8; ++i) {
        const int e = i * 1024 + t;            // coalesced
        myr[i] = rankof(xrow[e]);
        atomicAdd(&hist[myr[i]], 1u);
    }
    __syncthreads();
    if (t == 0) {                              // exclusive prefix (129 bins)
        unsigned run = 0;
        for (int b = 0; b < NRANK; ++b) { unsigned c = hist[b]; hist[b] = run; run += c; }
    }
    __syncthreads();
    #pragma unroll
    for (int i = 0; i < 8; ++i) {
        const int e = i * 1024 + t;
        unsigned pos = atomicAdd(&hist[myr[i]], 1u);
        permf[pos] = (unsigned)e | ((unsigned)myr[i] << 16);
    }
    __syncthreads();   // workgroup fence: perm visible to this block

    // ======== phase 2: MFMA batch loop, rank-sorted slices ========
    const int lane = t & 63, wv = t >> 6;   // 16 waves
    const int n = lane & 31, q2 = lane >> 5;

    // A-frags: A[m=lane&31][k=(lane>>5)*8+j] = W3[kk][ch=m]; 4 K-tiles of 16
    const float* __restrict__ w3g = W3 + f * NH2 * NH3;
    h16x8 A0, A1, A2, A3;
    #pragma unroll
    for (int j = 0; j < 8; ++j) {
        int kk = q2 * 8 + j;
        A0[j] = (_Float16)w3g[kk * NH3 + n];
        A1[j] = (_Float16)w3g[(kk + 16) * NH3 + n];
        A2[j] = (_Float16)w3g[(kk + 32) * NH3 + n];
        A3[j] = (_Float16)w3g[(kk + 48) * NH3 + n];
    }
    // bacc seeds the first MFMA's C operand; w4r for the layer-4 reduce
    f32x16 bacc;
    float w4r[16];
    #pragma unroll
    for (int reg = 0; reg < 16; ++reg) {
        int row = (reg & 3) + 8 * (reg >> 2) + 4 * q2;
        bacc[reg] = b3[f * NH3 + row];
        w4r[reg]  = W4[f * NH3 + row];
    }
    const float b4f = b4[f];

    // wave wv owns sorted positions [wv*512, wv*512+512)
    unsigned pr = permf[wv * 512 + n];         // round 0
    float   xv = xrow[pr & 0xFFFF];

    #pragma unroll 1
    for (int round = 0; round < 16; ++round) {
        // prefetch next round's perm word (wraps within slice; unused at end)
        const unsigned prn = permf[wv * 512 + ((round + 1) & 15) * 32 + n];

        const int r = (int)(pr >> 16);

        // gather lane's pair-dwords for its column n, row r; sorted ranks
        // make these same-address broadcasts across lanes (~free)
        const int ro = r * ROW4;
        u32x4 SW0 = SP4[ro + q2],      SW1 = SP4[ro + 2 + q2];
        u32x4 SW2 = SP4[ro + 4 + q2],  SW3 = SP4[ro + 6 + q2];
        u32x4 SB0 = SP4[ro + 8 + q2],  SB1 = SP4[ro + 10 + q2];
        u32x4 SB2 = SP4[ro + 12 + q2], SB3 = SP4[ro + 14 + q2];

        // B-frags: one pk_fma + pk_max per 2 channels
        const h16x2 xh = {(_Float16)xv, (_Float16)xv};
        u32x4 d0, d1, d2, d3;
        d0.x = pkh2(SW0.x, SB0.x, xh); d0.y = pkh2(SW0.y, SB0.y, xh);
        d0.z = pkh2(SW0.z, SB0.z, xh); d0.w = pkh2(SW0.w, SB0.w, xh);
        d1.x = pkh2(SW1.x, SB1.x, xh); d1.y = pkh2(SW1.y, SB1.y, xh);
        d1.z = pkh2(SW1.z, SB1.z, xh); d1.w = pkh2(SW1.w, SB1.w, xh);
        d2.x = pkh2(SW2.x, SB2.x, xh); d2.y = pkh2(SW2.y, SB2.y, xh);
        d2.z = pkh2(SW2.z, SB2.z, xh); d2.w = pkh2(SW2.w, SB2.w, xh);
        d3.x = pkh2(SW3.x, SB3.x, xh); d3.y = pkh2(SW3.y, SB3.y, xh);
        d3.z = pkh2(SW3.z, SB3.z, xh); d3.w = pkh2(SW3.w, SB3.w, xh);
        h16x8 B0 = __builtin_bit_cast(h16x8, d0);
        h16x8 B1 = __builtin_bit_cast(h16x8, d1);
        h16x8 B2 = __builtin_bit_cast(h16x8, d2);
        h16x8 B3 = __builtin_bit_cast(h16x8, d3);

        // layer 3: D[ch][batch], fp32 acc seeded with b3 rows via C operand
        f32x16 acc = __builtin_amdgcn_mfma_f32_32x32x16_f16(A0, B0, bacc, 0, 0, 0);
        acc = __builtin_amdgcn_mfma_f32_32x32x16_f16(A1, B1, acc, 0, 0, 0);
        acc = __builtin_amdgcn_mfma_f32_32x32x16_f16(A2, B2, acc, 0, 0, 0);
        acc = __builtin_amdgcn_mfma_f32_32x32x16_f16(A3, B3, acc, 0, 0, 0);

        // next round's x gather (L1-resident xrow) under the MFMA shadow
        const float xvn = xrow[prn & 0xFFFF];

        // layer 4: reduce lane's 16 rows; permlane cross-lane (VALU);
        // 1 atomic per element at its ORIGINAL index b (order-free).
        float p = 0.0f;
        #pragma unroll
        for (int reg = 0; reg < 16; ++reg)
            p = fmaf(fmaxf(acc[reg], 0.0f), w4r[reg], p);
        float pa = p, pb = p;
        asm volatile("v_permlane32_swap_b32 %0, %1" : "+v"(pa), "+v"(pb));
        if (lane < 32) atomicAdd(&out[pr & 0xFFFF], p + pb + b4f);

        pr = prn; xv = xvn;
    }
}

extern "C" void kernel_launch(void* const* d_in, const int* in_sizes, int n_in,
                              void* d_out, int out_size, void* d_ws, size_t ws_size,
                              hipStream_t stream) {
    const float* x    = (const float*)d_in[0];
    const float* W1   = (const float*)d_in[1];
    const float* b1   = (const float*)d_in[2];
    const float* W2   = (const float*)d_in[3];
    const float* b2   = (const float*)d_in[4];
    const float* W3   = (const float*)d_in[5];
    const float* b3   = (const float*)d_in[6];
    const float* W4   = (const float*)d_in[7];
    const float* b4   = (const float*)d_in[8];
    const float* bias = (const float*)d_in[9];
    float* out   = (float*)d_out;
    float* xtw   = (float*)d_ws;                       // xT: 8 MB
    unsigned* permw = (unsigned*)d_ws + (size_t)NF * NB;  // perm: 8 MB

    // transpose (both sides coalesced) + out-init
    transpose_x<<<512, 1024, 0, stream>>>(x, bias, out, xtw);
    // fused: 1 block/feature; table + rank-sort in LDS/ws, sorted MFMA loop
    nam_fused<<<NF, 1024, 0, stream>>>(W1, b1, W2, b2, W3, b3, W4, b4,
                                       xtw, permw, out);
}

// Round 13
// 110.181 us; speedup vs baseline: 1.7536x; 1.7536x over previous
//
#include <hip/hip_runtime.h>
#include <math.h>

// Neural Additive Model: 256 per-feature MLPs 1->128->64->32->1 (ReLU), summed.
// B=8192, fp32 in/out.
//
// Exact rank-table decomposition: pre-relu h2[b,k] = x_b*Sw[r,k] + Sb[r,k],
// r = #(sorted layer-1 thresholds < x_b). Layer 3 on f16 MFMA 32x32x16
// (A=W3^T, B=h2), layer 4 reduced in-register + 1 shfl, 1 atomic/elem.
//
// Round 30: GROUPED RANK PRECOMPUTE (conservative retry of R29's idea).
// R29 (16-deep arrays + full unroll + 16 tied-operand asm blocks) failed
// correctness -- a codegen hazard, not math (the precompute is pure code
// motion). R30 keeps the theory (in-loop rank walks serialize 4 dependent
// LDS reads ~480cy/round; precomputed they pipeline) with all risks removed:
//  - base = R25 exactly (dense walk levels, __shfl_xor epilogue -- the
//    5x-proven epilogue; permlane gained nothing in R27 anyway);
//  - groups of 4 rounds: 4 x-loads, then 4 INDEPENDENT rank walks (named
//    scalars, no arrays -> no scratch risk), then 4 static round bodies;
//  - outer group loop unroll 1 (code size bounded); zero inline asm.

#define NF   256
#define NH1  128
#define NH2  64
#define NH3  32
#define NB   8192

#define NRANK 129
#define ROW4  17                      // uint4 per table row (16 data + 1 pad)
#define ROWH  136                     // halfwords per row

typedef float    f32x16 __attribute__((ext_vector_type(16)));
typedef unsigned u32x4  __attribute__((ext_vector_type(4)));
typedef _Float16 h16x2  __attribute__((ext_vector_type(2)));
typedef _Float16 h16x8  __attribute__((ext_vector_type(8)));

// h2 pair: relu(x*Sw + Sb) on 2 packed f16 channels -> one B-frag dword
__device__ __forceinline__ unsigned pkh2(unsigned sw, unsigned sb, h16x2 xh) {
    h16x2 r = __builtin_elementwise_fma(xh, __builtin_bit_cast(h16x2, sw),
                                            __builtin_bit_cast(h16x2, sb));
    h16x2 hz = {(_Float16)0.f, (_Float16)0.f};
    return __builtin_bit_cast(unsigned, __builtin_elementwise_max(r, hz));
}

// ---------------- transpose: x[B][F] -> xT[F][B] in ws; fuses out-init ----------------
__global__ __launch_bounds__(1024) void transpose_x(
    const float* __restrict__ x, const float* __restrict__ bias,
    float* __restrict__ out, float* __restrict__ xt)
{
    __shared__ float xtile[64][65];        // padded -> conflict-free
    const int t = (int)threadIdx.x;
    const int T = blockIdx.x;              // 0..511
    const int bt = T >> 2, ft = T & 3;     // batch tile 0..127, feat tile 0..3

    if (T < 8) out[T * 1024 + t] = bias[0];   // out poisoned each launch

    #pragma unroll
    for (int it = 0; it < 4; ++it) {
        int idx = t + it * 1024;               // 4096 elems per tile
        int rr = idx >> 6, cc = idx & 63;      // read x[bt*64+rr][ft*64+cc]
        xtile[rr][cc] = x[(size_t)(bt * 64 + rr) * NF + ft * 64 + cc];
    }
    __syncthreads();
    #pragma unroll
    for (int it = 0; it < 4; ++it) {
        int idx = t + it * 1024;
        int cc = idx >> 6, rr = idx & 63;      // write xT[ft*64+cc][bt*64+rr]
        xt[(size_t)(ft * 64 + cc) * NB + bt * 64 + rr] = xtile[rr][cc];
    }
}

// ---------------- fused: one block (1024 thr) per feature ----------------
__global__ __launch_bounds__(1024) void nam_fused(
    const float* __restrict__ W1, const float* __restrict__ b1,
    const float* __restrict__ W2, const float* __restrict__ b2,
    const float* __restrict__ W3, const float* __restrict__ b3,
    const float* __restrict__ W4, const float* __restrict__ b4,
    const float* __restrict__ xt,
    float* __restrict__ out)
{
    __shared__ u32x4 SP4[NRANK * ROW4];    // 35.1 KB packed f16 table
    __shared__ float rkey[NH1];            // raw thresholds
    __shared__ float skey[NH1];            // sorted thresholds
    __shared__ int   sidx[NH1];            // sorted payload (channel idx)
    __shared__ float w1s[NH1], b1s[NH1];
    __shared__ float Pbw[16][NH2], Pbb[16][NH2], Pdw[16][NH2], Pdb[16][NH2]; // 16 KB
    __shared__ float lv8[8], lv4[16], lv2[32], lv1[64];  // dense walk levels

    const int f = blockIdx.x;
    const int t = (int)threadIdx.x;
    _Float16* SPh = (_Float16*)SP4;

    // ======== phase 1: build table (R21-proven math) ========
    const float* __restrict__ gw2 = W2 + (size_t)f * NH1 * NH2;
    if (t < NH1) {
        float w  = W1[f * NH1 + t];
        float bb = b1[f * NH1 + t];
        w1s[t] = w; b1s[t] = bb;
        rkey[t] = (w != 0.0f) ? (-bb / w) : INFINITY;   // w==0: never toggled
    }
    __syncthreads();

    // counting-rank sort: 128 threads, each ranks its key vs all 128
    if (t < NH1) {
        const float my = rkey[t];
        int rk = 0;
        #pragma unroll 16
        for (int i = 0; i < NH1; ++i) {
            float ki = rkey[i];
            rk += (ki < my || (ki == my && i < t)) ? 1 : 0;
        }
        skey[rk] = my; sidx[rk] = t;
    }
    __syncthreads();

    // dense walk levels (conflict-free rankof): consecutive addrs -> banks
    if (t < 8)            lv8[t]      = skey[t * 16 + 7];
    else if (t < 24)      lv4[t - 8]  = skey[(t - 8) * 8 + 3];
    else if (t < 56)      lv2[t - 24] = skey[(t - 24) * 4 + 1];
    else if (t < 120)     lv1[t - 56] = skey[(t - 56) * 2];

    // chunked scan: 1024 threads = (k = t&63) x (chunk c = t>>6, 8 j/ranks each)
    {
        const int k = t & 63, c = t >> 6;
        float bw = 0.0f, bbp = 0.0f, dw = 0.0f, db = 0.0f;
        #pragma unroll
        for (int i = 0; i < 8; ++i) {
            int j = c * 8 + i;    // rank-0 base: w<0 active; w==0&&b>0 const-on
            float w = w1s[j], bv = b1s[j], w2v = gw2[j * NH2 + k];
            if (w < 0.0f) { bw = fmaf(w, w2v, bw); bbp = fmaf(bv, w2v, bbp); }
            else if (w == 0.0f && bv > 0.0f) { bbp = fmaf(bv, w2v, bbp); }
            int jj = sidx[c * 8 + i];   // toggle-delta partial
            float ww = w1s[jj], bv2 = b1s[jj], w2x = gw2[jj * NH2 + k];
            float s = (ww > 0.0f) ? 1.0f : ((ww < 0.0f) ? -1.0f : 0.0f);
            dw = fmaf(s * ww,  w2x, dw);
            db = fmaf(s * bv2, w2x, db);
        }
        Pbw[c][k] = bw; Pbb[c][k] = bbp; Pdw[c][k] = dw; Pdb[c][k] = db;
    }
    __syncthreads();
    {
        const int k = t & 63, c = t >> 6;
        float accw = 0.0f;
        float accb = b2[f * NH2 + k];    // b2 seed (round-8 lesson)
        #pragma unroll
        for (int c2 = 0; c2 < 16; ++c2) { accw += Pbw[c2][k]; accb += Pbb[c2][k]; }
        for (int c2 = 0; c2 < c; ++c2) { accw += Pdw[c2][k]; accb += Pdb[c2][k]; }
        // layout per row: Sw halves [0..63], Sb halves [64..127], pad to 136
        if (c == 0) {
            SPh[k]      = (_Float16)accw;          // rank-0 row
            SPh[64 + k] = (_Float16)accb;
        }
        #pragma unroll
        for (int i = 0; i < 8; ++i) {
            int r = c * 8 + i;
            int j = sidx[r];                       // uniform per chunk -> broadcast
            float w = w1s[j], bv = b1s[j], w2v = gw2[j * NH2 + k];
            float s = (w > 0.0f) ? 1.0f : ((w < 0.0f) ? -1.0f : 0.0f);
            accw = fmaf(s * w,  w2v, accw);
            accb = fmaf(s * bv, w2v, accb);
            SPh[(r + 1) * ROWH + k]      = (_Float16)accw;
            SPh[(r + 1) * ROWH + 64 + k] = (_Float16)accb;
        }
    }
    __syncthreads();

    // ======== phase 2: MFMA batch loop, walks precomputed per group of 4 ========
    const int lane = t & 63, wv = t >> 6;   // 16 waves
    const int n = lane & 31, q2 = lane >> 5;

    // A-frags: A[m=lane&31][k=(lane>>5)*8+j] = W3[kk][ch=m]; 4 K-tiles of 16
    const float* __restrict__ w3g = W3 + f * NH2 * NH3;
    h16x8 A0, A1, A2, A3;
    #pragma unroll
    for (int j = 0; j < 8; ++j) {
        int kk = q2 * 8 + j;
        A0[j] = (_Float16)w3g[kk * NH3 + n];
        A1[j] = (_Float16)w3g[(kk + 16) * NH3 + n];
        A2[j] = (_Float16)w3g[(kk + 32) * NH3 + n];
        A3[j] = (_Float16)w3g[(kk + 48) * NH3 + n];
    }
    // bacc seeds the first MFMA's C operand; w4r for the layer-4 reduce
    f32x16 bacc;
    float w4r[16];
    #pragma unroll
    for (int reg = 0; reg < 16; ++reg) {
        int row = (reg & 3) + 8 * (reg >> 2) + 4 * q2;
        bacc[reg] = b3[f * NH3 + row];
        w4r[reg]  = W4[f * NH3 + row];
    }
    const float b4f = b4[f];
    const float* __restrict__ xrow = xt + (size_t)f * NB;   // coalesced x
    // register-tree search levels s=64/32/16 (7 thresholds)
    const float t63 = skey[63], t31 = skey[31], t95 = skey[95];
    const float t15 = skey[15], t47 = skey[47], t79 = skey[79], t111 = skey[111];

    // rank = #(skey < q): 3 register levels + 4 conflict-free LDS levels
    auto rankof = [&](float q) -> int {
        int rr = (t63 < q) ? 64 : 0;
        {
            float l1 = (rr & 64) ? t95 : t31;
            if (l1 < q) rr += 32;
            float m0 = (rr & 64) ? t79  : t15;
            float m1 = (rr & 64) ? t111 : t47;
            float l2 = (rr & 32) ? m1 : m0;
            if (l2 < q) rr += 16;
        }
        if (lv8[rr >> 4] < q) rr += 8;
        if (lv4[rr >> 3] < q) rr += 4;
        if (lv2[rr >> 2] < q) rr += 2;
        if (lv1[rr >> 1] < q) rr += 1;
        return rr;
    };

    auto bat = [&](int round) -> int {
        return (((round + f) & 15) * 16 + wv) * 32 + n;
    };

    // one round body (static args; compiler inlines)
    auto round_body = [&](int round, float xv, int r) {
        const int base = (((round + f) & 15) * 16 + wv) * 32;
        const int ro = r * ROW4;
        u32x4 SW0 = SP4[ro + q2],      SW1 = SP4[ro + 2 + q2];
        u32x4 SW2 = SP4[ro + 4 + q2],  SW3 = SP4[ro + 6 + q2];
        u32x4 SB0 = SP4[ro + 8 + q2],  SB1 = SP4[ro + 10 + q2];
        u32x4 SB2 = SP4[ro + 12 + q2], SB3 = SP4[ro + 14 + q2];

        const h16x2 xh = {(_Float16)xv, (_Float16)xv};
        u32x4 d0, d1, d2, d3;
        d0.x = pkh2(SW0.x, SB0.x, xh); d0.y = pkh2(SW0.y, SB0.y, xh);
        d0.z = pkh2(SW0.z, SB0.z, xh); d0.w = pkh2(SW0.w, SB0.w, xh);
        d1.x = pkh2(SW1.x, SB1.x, xh); d1.y = pkh2(SW1.y, SB1.y, xh);
        d1.z = pkh2(SW1.z, SB1.z, xh); d1.w = pkh2(SW1.w, SB1.w, xh);
        d2.x = pkh2(SW2.x, SB2.x, xh); d2.y = pkh2(SW2.y, SB2.y, xh);
        d2.z = pkh2(SW2.z, SB2.z, xh); d2.w = pkh2(SW2.w, SB2.w, xh);
        d3.x = pkh2(SW3.x, SB3.x, xh); d3.y = pkh2(SW3.y, SB3.y, xh);
        d3.z = pkh2(SW3.z, SB3.z, xh); d3.w = pkh2(SW3.w, SB3.w, xh);
        h16x8 B0 = __builtin_bit_cast(h16x8, d0);
        h16x8 B1 = __builtin_bit_cast(h16x8, d1);
        h16x8 B2 = __builtin_bit_cast(h16x8, d2);
        h16x8 B3 = __builtin_bit_cast(h16x8, d3);

        f32x16 acc = __builtin_amdgcn_mfma_f32_32x32x16_f16(A0, B0, bacc, 0, 0, 0);
        acc = __builtin_amdgcn_mfma_f32_32x32x16_f16(A1, B1, acc, 0, 0, 0);
        acc = __builtin_amdgcn_mfma_f32_32x32x16_f16(A2, B2, acc, 0, 0, 0);
        acc = __builtin_amdgcn_mfma_f32_32x32x16_f16(A3, B3, acc, 0, 0, 0);

        float p = 0.0f;
        #pragma unroll
        for (int reg = 0; reg < 16; ++reg)
            p = fmaf(fmaxf(acc[reg], 0.0f), w4r[reg], p);
        p += __shfl_xor(p, 32);
        if (lane < 32) atomicAdd(&out[base + lane], p + b4f);
    };

    // 4 groups x 4 rounds: x-loads then 4 INDEPENDENT walks (pipeline at
    // LDS throughput, not 4x480cy serial), then 4 static round bodies.
    #pragma unroll 1
    for (int g = 0; g < 4; ++g) {
        const int rb = g * 4;
        const float xa = xrow[bat(rb + 0)];
        const float xb = xrow[bat(rb + 1)];
        const float xc = xrow[bat(rb + 2)];
        const float xd = xrow[bat(rb + 3)];
        const int ra = rankof(xa);
        const int rc2 = rankof(xc);          // interleave: independent walks
        const int rbk = rankof(xb);
        const int rd = rankof(xd);

        round_body(rb + 0, xa, ra);
        round_body(rb + 1, xb, rbk);
        round_body(rb + 2, xc, rc2);
        round_body(rb + 3, xd, rd);
    }
}

extern "C" void kernel_launch(void* const* d_in, const int* in_sizes, int n_in,
                              void* d_out, int out_size, void* d_ws, size_t ws_size,
                              hipStream_t stream) {
    const float* x    = (const float*)d_in[0];
    const float* W1   = (const float*)d_in[1];
    const float* b1   = (const float*)d_in[2];
    const float* W2   = (const float*)d_in[3];
    const float* b2   = (const float*)d_in[4];
    const float* W3   = (const float*)d_in[5];
    const float* b3   = (const float*)d_in[6];
    const float* W4   = (const float*)d_in[7];
    const float* b4   = (const float*)d_in[8];
    const float* bias = (const float*)d_in[9];
    float* out   = (float*)d_out;
    float* xtw   = (float*)d_ws;      // ws holds xT: 8 MB

    // transpose (both sides coalesced) + out-init
    transpose_x<<<512, 1024, 0, stream>>>(x, bias, out, xtw);
    // fused: 1 block/feature = 1 block/CU; table lives and dies in LDS
    nam_fused<<<NF, 1024, 0, stream>>>(W1, b1, W2, b2, W3, b3, W4, b4,
                                       xtw, out);
}